// Round 3
// baseline (470.638 us; speedup 1.0000x reference)
//
#include <hip/hip_runtime.h>

// TopK (K=64) per row, B=4096 x D=16384 fp32.
// out = zeros; out[row, top64 idx] = value.
//
// R3: no LDS row staging (R2's 64 KiB stage capped occupancy at 2 blocks/CU
// and forced 4 full LDS scans). Instead: S1 streams the row from global and
// builds a 2048-bin histogram of the top-11 ordered bits; a suffix scan
// selects the boundary bin B0 + rem. S2 re-streams the row (L2/L3-warm),
// writes bin>B0 ? val : 0 directly, and collects bin==B0 candidates
// (~100-300 for normal data) into LDS. Exact threshold + lowest-index-first
// ties resolved by rank-select over the candidate list, then scalar fix-ups.
// LDS ~24.5 KiB -> 6 blocks/CU; 256 thr/block, 64 values/thread.

#define TK_D      16384
#define TK_K      64
#define TK_T      256          // threads per block
#define TK_C4     16           // float4 chunks per thread (TK_D/4/TK_T)
#define TK_BINS   2048         // top-11 ordered bits
#define TK_BPT    8            // bins per thread (TK_BINS/TK_T)
#define TK_CAP    2048         // candidate cap (selected bin ~300 max for
                               // normal data near the K/D=0.4% boundary)

__device__ __forceinline__ unsigned ord_map(unsigned b) {
    // larger u <=> larger float (handles negatives)
    return b ^ ((unsigned)((int)b >> 31) | 0x80000000u);
}
__device__ __forceinline__ float ord_unmap(unsigned u) {
    return __uint_as_float(u ^ ((unsigned)((int)(~u) >> 31) | 0x80000000u));
}

__launch_bounds__(TK_T, 6)
__global__ void topk_scatter_kernel(const float* __restrict__ x,
                                    float* __restrict__ out) {
    __shared__ int      sh_hist[TK_BINS];     // 8 KiB
    __shared__ unsigned sh_cu[TK_CAP];        // candidate ordered-uints, 8 KiB
    __shared__ int      sh_ci[TK_CAP];        // candidate columns, 8 KiB
    __shared__ int      sh_wsum[4];
    __shared__ unsigned sh_B0;
    __shared__ int      sh_rem;
    __shared__ int      sh_cn;
    __shared__ unsigned sh_T;
    __shared__ int      sh_gT;

    const int row  = blockIdx.x;
    const int tid  = threadIdx.x;
    const int lane = tid & 63;
    const int wv   = tid >> 6;

    const float4* __restrict__ xrow = (const float4*)(x + (size_t)row * TK_D);
    float4* __restrict__ orow       = (float4*)(out + (size_t)row * TK_D);

    // zero histogram (8 bins/thread) + flags
    ((int4*)sh_hist)[2 * tid]     = int4{0, 0, 0, 0};
    ((int4*)sh_hist)[2 * tid + 1] = int4{0, 0, 0, 0};
    if (tid == 0) sh_cn = 0;
    __syncthreads();

    // ---- S1: stream row, histogram top-11 ordered bits ----
    #pragma unroll
    for (int i = 0; i < TK_C4; i++) {
        float4 v = xrow[tid + i * TK_T];
        #pragma unroll
        for (int c = 0; c < 4; c++) {
            unsigned u = ord_map(__float_as_uint(((const float*)&v)[c]));
            atomicAdd(&sh_hist[u >> 21], 1);
        }
    }
    __syncthreads();

    // ---- select boundary bin: suffix scan over 2048 bins ----
    {
        int h[TK_BPT];
        #pragma unroll
        for (int c = 0; c < TK_BPT; c++) h[c] = sh_hist[TK_BPT * tid + c];
        int local = 0;
        #pragma unroll
        for (int c = 0; c < TK_BPT; c++) local += h[c];
        int suf = local;                       // -> sum over lanes >= lane
        #pragma unroll
        for (int off = 1; off < 64; off <<= 1) {
            int o = __shfl_down(suf, off);
            if (lane + off < 64) suf += o;
        }
        if (lane == 0) sh_wsum[wv] = suf;
        __syncthreads();
        int above = suf - local;               // within-wave lanes above
        #pragma unroll
        for (int w2 = 0; w2 < 4; w2++)
            if (w2 > wv) above += sh_wsum[w2];
        // bins of this thread, descending index
        int s_excl = above;
        #pragma unroll
        for (int c = TK_BPT - 1; c >= 0; c--) {
            int S = s_excl + h[c];
            if (S >= TK_K && s_excl < TK_K) {  // exactly one bin globally
                sh_B0  = (unsigned)(TK_BPT * tid + c);
                sh_rem = TK_K - s_excl;
            }
            s_excl = S;
        }
    }
    __syncthreads();
    const unsigned B0   = sh_B0;
    const int      remB = sh_rem;              // needed from bin B0, >= 1

    // ---- S2: re-stream row; write resolved values; collect candidates ----
    #pragma unroll
    for (int i = 0; i < TK_C4; i++) {
        const int c4 = tid + i * TK_T;
        float4 v = xrow[c4];
        float4 o;
        #pragma unroll
        for (int c = 0; c < 4; c++) {
            float    f   = ((const float*)&v)[c];
            unsigned u   = ord_map(__float_as_uint(f));
            unsigned bin = u >> 21;
            ((float*)&o)[c] = (bin > B0) ? f : 0.0f;
            if (bin == B0) {
                int pos = atomicAdd(&sh_cn, 1);
                if (pos < TK_CAP) { sh_cu[pos] = u; sh_ci[pos] = 4 * c4 + c; }
            }
        }
        orow[c4] = o;
    }
    __syncthreads();

    // ---- rank-select exact threshold among candidates ----
    const int C = min(sh_cn, TK_CAP);
    for (int i = tid; i < C; i += TK_T) {
        unsigned ui = sh_cu[i];
        int g = 0, e = 0;
        for (int j = 0; j < C; j++) {
            unsigned uj = sh_cu[j];            // broadcast read
            g += (uj > ui);
            e += (uj == ui);
        }
        if (g < remB && g + e >= remB) { sh_T = ui; sh_gT = g; }
    }
    __syncthreads();
    const unsigned T    = sh_T;
    const int      need = remB - sh_gT;        // ties accepted, >= 1

    // ---- fix up candidates: u > T always; ties lowest-column-first ----
    for (int i = tid; i < C; i += TK_T) {
        unsigned ui = sh_cu[i];
        if (ui > T) {
            out[(size_t)row * TK_D + sh_ci[i]] = ord_unmap(ui);
        } else if (ui == T) {
            int ci = sh_ci[i], r = 0;
            for (int j = 0; j < C; j++)
                r += (sh_cu[j] == T && sh_ci[j] < ci);
            if (r < need)
                out[(size_t)row * TK_D + ci] = ord_unmap(ui);
        }
    }
}

extern "C" void kernel_launch(void* const* d_in, const int* in_sizes, int n_in,
                              void* d_out, int out_size, void* d_ws, size_t ws_size,
                              hipStream_t stream) {
    const float* x = (const float*)d_in[0];
    float* out = (float*)d_out;
    const int B = in_sizes[0] / TK_D;          // 4096
    topk_scatter_kernel<<<B, TK_T, 0, stream>>>(x, out);
}

// Round 5
// 468.645 us; speedup vs baseline: 1.0043x; 1.0043x over previous
//
#include <hip/hip_runtime.h>

// TopK (K=64) per row, B=4096 x D=16384 fp32.
// out = zeros; out[row, top64 idx] = value.
//
// R5 = R4 with the nontemporal-store compile fix (clang ext_vector float4).
// Algorithm: S1 histogram top-11 ordered bits -> boundary bin B0 + rem;
// S2 re-stream (cache-warm), write bin>B0?val:0 via nontemporal stores,
// collect bin==B0 candidates; exact rank-select + lowest-index-first ties.
// Latency fixes vs R3: batch-16 float4 loads held in registers in both
// passes (MLP), __launch_bounds__(256,4) -> 128-VGPR budget, 4 blocks/CU.

#define TK_D      16384
#define TK_K      64
#define TK_T      256          // threads per block
#define TK_C4     16           // float4 chunks per thread (TK_D/4/TK_T)
#define TK_BINS   2048         // top-11 ordered bits
#define TK_BPT    8            // bins per thread (TK_BINS/TK_T)
#define TK_CAP    2048         // candidate cap (boundary bin ~100-300 for
                               // normal data at the K/D=0.4% quantile)

typedef float  fx4 __attribute__((ext_vector_type(4)));   // nt-store friendly

__device__ __forceinline__ unsigned ord_map(unsigned b) {
    // larger u <=> larger float (handles negatives)
    return b ^ ((unsigned)((int)b >> 31) | 0x80000000u);
}
__device__ __forceinline__ float ord_unmap(unsigned u) {
    return __uint_as_float(u ^ ((unsigned)((int)(~u) >> 31) | 0x80000000u));
}

__launch_bounds__(TK_T, 4)
__global__ void topk_scatter_kernel(const float* __restrict__ x,
                                    float* __restrict__ out) {
    __shared__ int      sh_hist[TK_BINS];     // 8 KiB
    __shared__ unsigned sh_cu[TK_CAP];        // candidate ordered-uints, 8 KiB
    __shared__ int      sh_ci[TK_CAP];        // candidate columns, 8 KiB
    __shared__ int      sh_wsum[4];
    __shared__ unsigned sh_B0;
    __shared__ int      sh_rem;
    __shared__ int      sh_cn;
    __shared__ unsigned sh_T;
    __shared__ int      sh_gT;

    const int row  = blockIdx.x;
    const int tid  = threadIdx.x;
    const int lane = tid & 63;
    const int wv   = tid >> 6;

    const fx4* __restrict__ xrow = (const fx4*)(x + (size_t)row * TK_D);
    fx4* __restrict__ orow       = (fx4*)(out + (size_t)row * TK_D);

    // zero histogram (8 bins/thread) + flags
    ((int4*)sh_hist)[2 * tid]     = int4{0, 0, 0, 0};
    ((int4*)sh_hist)[2 * tid + 1] = int4{0, 0, 0, 0};
    if (tid == 0) sh_cn = 0;
    __syncthreads();

    // ---- S1: stream row (all 16 loads in flight), histogram top-11 bits ----
    {
        fx4 v[TK_C4];
        #pragma unroll
        for (int i = 0; i < TK_C4; i++) v[i] = xrow[tid + i * TK_T];
        #pragma unroll
        for (int i = 0; i < TK_C4; i++) {
            #pragma unroll
            for (int c = 0; c < 4; c++) {
                unsigned u = ord_map(__float_as_uint(v[i][c]));
                atomicAdd(&sh_hist[u >> 21], 1);
            }
        }
    }
    __syncthreads();

    // ---- select boundary bin: suffix scan over 2048 bins ----
    {
        int h[TK_BPT];
        #pragma unroll
        for (int c = 0; c < TK_BPT; c++) h[c] = sh_hist[TK_BPT * tid + c];
        int local = 0;
        #pragma unroll
        for (int c = 0; c < TK_BPT; c++) local += h[c];
        int suf = local;                       // -> sum over lanes >= lane
        #pragma unroll
        for (int off = 1; off < 64; off <<= 1) {
            int o = __shfl_down(suf, off);
            if (lane + off < 64) suf += o;
        }
        if (lane == 0) sh_wsum[wv] = suf;
        __syncthreads();
        int above = suf - local;               // within-wave lanes above
        #pragma unroll
        for (int w2 = 0; w2 < 4; w2++)
            if (w2 > wv) above += sh_wsum[w2];
        // bins of this thread, descending index
        int s_excl = above;
        #pragma unroll
        for (int c = TK_BPT - 1; c >= 0; c--) {
            int S = s_excl + h[c];
            if (S >= TK_K && s_excl < TK_K) {  // exactly one bin globally
                sh_B0  = (unsigned)(TK_BPT * tid + c);
                sh_rem = TK_K - s_excl;
            }
            s_excl = S;
        }
    }
    __syncthreads();
    const unsigned B0   = sh_B0;
    const int      remB = sh_rem;              // needed from bin B0, >= 1

    // ---- S2: re-stream row (cache-warm, all loads in flight);
    //      write resolved values nontemporally; collect candidates ----
    {
        fx4 v[TK_C4];
        #pragma unroll
        for (int i = 0; i < TK_C4; i++) v[i] = xrow[tid + i * TK_T];
        #pragma unroll
        for (int i = 0; i < TK_C4; i++) {
            const int c4 = tid + i * TK_T;
            fx4 o;
            #pragma unroll
            for (int c = 0; c < 4; c++) {
                float    f   = v[i][c];
                unsigned u   = ord_map(__float_as_uint(f));
                unsigned bin = u >> 21;
                o[c] = (bin > B0) ? f : 0.0f;
                if (bin == B0) {
                    int pos = atomicAdd(&sh_cn, 1);
                    if (pos < TK_CAP) { sh_cu[pos] = u; sh_ci[pos] = 4 * c4 + c; }
                }
            }
            __builtin_nontemporal_store(o, &orow[c4]);
        }
    }
    __syncthreads();

    // ---- rank-select exact threshold among candidates ----
    const int C = min(sh_cn, TK_CAP);
    for (int i = tid; i < C; i += TK_T) {
        unsigned ui = sh_cu[i];
        int g = 0, e = 0;
        for (int j = 0; j < C; j++) {
            unsigned uj = sh_cu[j];            // broadcast read
            g += (uj > ui);
            e += (uj == ui);
        }
        if (g < remB && g + e >= remB) { sh_T = ui; sh_gT = g; }
    }
    __syncthreads();
    const unsigned T    = sh_T;
    const int      need = remB - sh_gT;        // ties accepted, >= 1

    // ---- fix up candidates: u > T always; ties lowest-column-first ----
    for (int i = tid; i < C; i += TK_T) {
        unsigned ui = sh_cu[i];
        if (ui > T) {
            out[(size_t)row * TK_D + sh_ci[i]] = ord_unmap(ui);
        } else if (ui == T) {
            int ci = sh_ci[i], r = 0;
            for (int j = 0; j < C; j++)
                r += (sh_cu[j] == T && sh_ci[j] < ci);
            if (r < need)
                out[(size_t)row * TK_D + ci] = ord_unmap(ui);
        }
    }
}

extern "C" void kernel_launch(void* const* d_in, const int* in_sizes, int n_in,
                              void* d_out, int out_size, void* d_ws, size_t ws_size,
                              hipStream_t stream) {
    const float* x = (const float*)d_in[0];
    float* out = (float*)d_out;
    const int B = in_sizes[0] / TK_D;          // 4096
    topk_scatter_kernel<<<B, TK_T, 0, stream>>>(x, out);
}